// Round 10
// baseline (627.611 us; speedup 1.0000x reference)
//
#include <hip/hip_runtime.h>
#include <math.h>

// Problem constants: B=1024, T=256, D=128, H=64, 4H=256
constexpr int B_ = 1024;
constexpr int T_ = 256;
constexpr int D_ = 128;
constexpr int H_ = 64;
constexpr int G_ = 256;
constexpr int M_ = B_ * T_;

typedef short     v8s __attribute__((ext_vector_type(8)));   // 8 bf16
typedef float     v4f __attribute__((ext_vector_type(4)));   // MFMA acc
typedef _Float16  v8h __attribute__((ext_vector_type(8)));   // 8 f16 (MFMA A/B)
typedef _Float16  h2  __attribute__((ext_vector_type(2)));   // packed f16

__device__ __forceinline__ float sigmoidf_(float x) {
    return 1.0f / (1.0f + __expf(-x));
}
// tanh(x) = 2*sigmoid(2x) - 1 ; overflow-safe at both ends
__device__ __forceinline__ float tanhf_(float x) {
    return fmaf(2.0f, 1.0f / (1.0f + __expf(-2.0f * x)), -1.0f);
}
__device__ __forceinline__ unsigned short f2bf(float f) {   // RNE f32->bf16
    unsigned u = __float_as_uint(f);
    u = (u + 0x7fffu + ((u >> 16) & 1u)) >> 16;
    return (unsigned short)u;
}
__device__ __forceinline__ v8s pack8(float4 a, float4 b) {
    v8s r;
    r[0] = (short)f2bf(a.x); r[1] = (short)f2bf(a.y);
    r[2] = (short)f2bf(a.z); r[3] = (short)f2bf(a.w);
    r[4] = (short)f2bf(b.x); r[5] = (short)f2bf(b.y);
    r[6] = (short)f2bf(b.z); r[7] = (short)f2bf(b.w);
    return r;
}
__device__ __forceinline__ unsigned pkh2(float a, float b) {  // 2xf32 -> packed f16
    h2 v; v[0] = (_Float16)a; v[1] = (_Float16)b;
    return __builtin_bit_cast(unsigned, v);
}

// ---------------------------------------------------------------------------
// Phase 1 (R1 measured-good, unchanged): xp[b][t][g] (f16, bias folded)
// = W_ih @ x^T. 1024 blocks (16 t x 64 batch-blocks), 256 thr.
// ---------------------------------------------------------------------------
__global__ __launch_bounds__(256, 2)
void xproj_f16_kernel(const float* __restrict__ x,       // [B,T,D]
                      const float* __restrict__ W_ih,    // [256,128]
                      const float* __restrict__ b_ih,    // [256]
                      const float* __restrict__ b_hh,    // [256]
                      unsigned short* __restrict__ xp)   // [B][T][256] f16
{
    const int tch  = blockIdx.x;     // 0..15 : t = tch*16 + tl
    const int bblk = blockIdx.y;     // 0..63 : batches bblk*16..+15
    const int tid  = threadIdx.x;
    const int wv   = tid >> 6;
    const int lane = tid & 63;
    const int q    = lane >> 4;
    const int ml   = lane & 15;

    __shared__ __align__(16) unsigned short xs[16][136];   // x tile bf16, pad+8
    __shared__ __align__(16) unsigned short tbuf[16][272]; // [batch][gate] f16

    // ---- wave-resident A-frags + bias: gate tiles gt = cls*4 + wv ----
    v8s afr[4][4];   // [cls][ks]
    v4f bias[4];
    #pragma unroll
    for (int cls = 0; cls < 4; ++cls) {
        const int gr = (cls * 4 + wv) * 16 + ml;       // A m-index = ml
        #pragma unroll
        for (int ks = 0; ks < 4; ++ks) {
            const float* p = W_ih + (size_t)gr * D_ + ks * 32 + q * 8;
            afr[cls][ks] = pack8(((const float4*)p)[0], ((const float4*)p)[1]);
        }
        #pragma unroll
        for (int r = 0; r < 4; ++r) {
            const int g2 = (cls * 4 + wv) * 16 + q * 4 + r;   // C row = q*4+r
            bias[cls][r] = b_ih[g2] + b_hh[g2];
        }
    }

    for (int tl = 0; tl < 16; ++tl) {
        const int t = tch * 16 + tl;

        // ---- stage x tile: 16 batches x 128 f32 -> bf16 LDS ----
        #pragma unroll
        for (int i = 0; i < 2; ++i) {
            int f4  = tid + i * 256;          // 512 float4s
            int row = f4 >> 5, c4 = f4 & 31;
            float4 v = ((const float4*)(x + ((size_t)(bblk * 16 + row) * T_
                                             + t) * D_))[c4];
            short4 s;
            s.x = (short)f2bf(v.x); s.y = (short)f2bf(v.y);
            s.z = (short)f2bf(v.z); s.w = (short)f2bf(v.w);
            *(short4*)&xs[row][c4 * 4] = s;
        }
        __syncthreads();   // bar1: xs ready (also protects prev tbuf readers)

        // ---- MFMA: 4 C-tiles per wave, K=128 ----
        v4f acc[4];
        #pragma unroll
        for (int cls = 0; cls < 4; ++cls) acc[cls] = bias[cls];
        #pragma unroll
        for (int ks = 0; ks < 4; ++ks) {
            v8s bf = *(const v8s*)&xs[ml][ks * 32 + q * 8];   // B: n=ml, k
            #pragma unroll
            for (int cls = 0; cls < 4; ++cls)
                acc[cls] = __builtin_amdgcn_mfma_f32_16x16x32_bf16(
                    afr[cls][ks], bf, acc[cls], 0, 0, 0);
        }

        // ---- pack f16 -> tbuf[batch=ml][gate] ----
        #pragma unroll
        for (int cls = 0; cls < 4; ++cls) {
            uint2 pk;
            pk.x = pkh2(acc[cls][0], acc[cls][1]);
            pk.y = pkh2(acc[cls][2], acc[cls][3]);
            *(uint2*)&tbuf[ml][cls * 64 + wv * 16 + q * 4] = pk;
        }
        __syncthreads();   // bar2: tbuf ready; all xs reads done

        // ---- coalesced store: thread covers 16 gates of one (b,t) row ----
        {
            const int br = tid >> 4, seg = tid & 15;
            uint4 r0 = *(const uint4*)&tbuf[br][seg * 16];
            uint4 r1 = *(const uint4*)&tbuf[br][seg * 16 + 8];
            unsigned short* orow = xp + ((size_t)(bblk * 16 + br) * T_ + t) * G_
                                      + seg * 16;
            *(uint4*)orow       = r0;
            *(uint4*)(orow + 8) = r1;
        }
    }
}

// ---------------------------------------------------------------------------
// Phase 2 (R10): MFMA recurrence. One wave = 4 batches; the h@W_hh^T matvec
// runs on the matrix pipe instead of 128 VALU dot2s (the measured ~1024
// cy/step issue cost that dominates R1's 1575 cy step).
//   A (resident, 128 VGPR): W_hh row-tiles: A[t][kb], rows 16t+ml,
//     k = kb*32 + q*8..+7, f16  (same frag layout as the WORKING xproj MFMA).
//   B (2 ds_read_b128/step): B[k][n] = h_{n&3}[kb*32+k] -- the 4 batches' h
//     replicated over the 16 columns; lane reads hbuf[ml&3][kb*32+q*8..].
//   C: lane(q,ml) holds rows q*4+j of every tile, col ml (m89 layout, live-
//     verified by xproj). With batch=ml&3, a=ml>>2: lane statically owns
//     i,f,g,o of units u_s = 16s+q*4+a (s=0..3): i=acc[s], f=acc[s+4],
//     g=acc[s+8], o=acc[s+12], at reg 'a' (3 cndmask selects, no scratch,
//     no divergence). 64 lanes x 4 units x 4 batches = full coverage.
// h stays in wave-local LDS (R7: shfl/readlane lose); no barriers (R4);
// W resident in VGPRs (R6); 64-thr block (R8/R9: 512-thr caps VGPR at 128).
// f16 MFMA keeps numerics identical to the f16-dot2 path.
// ---------------------------------------------------------------------------
__global__ __launch_bounds__(64, 1)
void rec_mfma_kernel(const unsigned short* __restrict__ xp,  // [B][T][256] f16
                     const float* __restrict__ W_hh,   // [256,64]
                     const float* __restrict__ W1,     // [32,64]
                     const float* __restrict__ b1,     // [32]
                     const float* __restrict__ W2,     // [1,32]
                     const float* __restrict__ b2,     // [1]
                     float* __restrict__ out)          // [B]
{
    const int lane = threadIdx.x;    // 0..63
    const int q    = lane >> 4;      // 0..3 : C row group / B,A k-group
    const int ml   = lane & 15;      // 0..15: C col / A row / B col
    const int bb   = ml & 3;         // batch slot 0..3
    const int a    = ml >> 2;        // C reg select 0..3
    const int batch = blockIdx.x * 4 + bb;

    __shared__ __align__(16) _Float16 hbuf[4][80];   // h f16, rows padded to
                                                     // 160B (bank spread)
    __shared__ float ys[32];

    // ---- A-frags: W_hh rows 16t+ml, cols kb*32+q*8..+7, f16 (128 VGPR) ----
    v8h A[16][2];
    #pragma unroll
    for (int t = 0; t < 16; ++t) {
        const float* wr = W_hh + (size_t)(16 * t + ml) * H_;
        #pragma unroll
        for (int kb = 0; kb < 2; ++kb) {
            const float* p = wr + kb * 32 + q * 8;
            float4 v0 = ((const float4*)p)[0];
            float4 v1 = ((const float4*)p)[1];
            v8h f;
            f[0] = (_Float16)v0.x; f[1] = (_Float16)v0.y;
            f[2] = (_Float16)v0.z; f[3] = (_Float16)v0.w;
            f[4] = (_Float16)v1.x; f[5] = (_Float16)v1.y;
            f[6] = (_Float16)v1.z; f[7] = (_Float16)v1.w;
            A[t][kb] = f;
        }
    }

    // ---- h(0) = 0 ----
    {
        unsigned* hz = (unsigned*)&hbuf[0][0];       // 160 dwords
        for (int i = lane; i < 160; i += 64) hz[i] = 0u;
    }
    asm volatile("s_waitcnt lgkmcnt(0)" ::: "memory");

    float c[4] = {0.f, 0.f, 0.f, 0.f};
    const unsigned short* __restrict__ xrow =
        xp + (size_t)batch * T_ * G_ + q * 4 + a;

    for (int t = 0; t < T_; ++t) {
        // ---- xp for this step: 16 gate-rows 16*tt+q*4+a (issued first,
        //      consumed after the MFMA block -> latency mostly covered) ----
        unsigned short xv[16];
        #pragma unroll
        for (int tt = 0; tt < 16; ++tt)
            xv[tt] = xrow[(size_t)t * G_ + 16 * tt];

        // ---- B-frags: h replicated across columns (broadcast b128) ----
        v8h B0 = *(const v8h*)&hbuf[bb][q * 8];
        v8h B1 = *(const v8h*)&hbuf[bb][32 + q * 8];

        // ---- 32 MFMA: gates[256] x 4 batches on the matrix pipe ----
        v4f acc[16];
        #pragma unroll
        for (int s = 0; s < 16; ++s) {
            v4f z = {0.f, 0.f, 0.f, 0.f};
            z = __builtin_amdgcn_mfma_f32_16x16x32_f16(A[s][0], B0, z, 0, 0, 0);
            acc[s] = __builtin_amdgcn_mfma_f32_16x16x32_f16(A[s][1], B1, z,
                                                            0, 0, 0);
        }

        // ---- extract reg 'a' (static cndmask tree) + xp add ----
        float pre[16];
        #pragma unroll
        for (int s = 0; s < 16; ++s) {
            float lo = (a & 1) ? acc[s][1] : acc[s][0];
            float hi = (a & 1) ? acc[s][3] : acc[s][2];
            float v  = (a & 2) ? hi : lo;
            pre[s] = v + (float)__builtin_bit_cast(_Float16, xv[s]);
        }

        // ---- 4 lane-local cell updates: unit u_s = 16s + q*4 + a ----
        #pragma unroll
        for (int s = 0; s < 4; ++s) {
            float gi = sigmoidf_(pre[s]);
            float gf = sigmoidf_(pre[s + 4]);
            float gg = tanhf_(pre[s + 8]);
            float go = sigmoidf_(pre[s + 12]);
            c[s] = fmaf(gf, c[s], gi * gg);
            float hv = go * tanhf_(c[s]);
            hbuf[bb][16 * s + q * 4 + a] = (_Float16)hv;
        }
        // wave-local LDS fence (single wave: in-order DS pipe; this just
        // pins the schedule). No barrier, no vmcnt drain.
        asm volatile("s_waitcnt lgkmcnt(0)" ::: "memory");
    }

    // ---- head: 4 batches, computed from hbuf (single wave, fence-only) ----
    for (int pb = 0; pb < 4; ++pb) {
        if (lane < 32) {
            float acc = b1[lane];
            const float4* w1r = (const float4*)(W1 + (size_t)lane * H_);
            #pragma unroll
            for (int k4 = 0; k4 < 16; ++k4) {
                float4 w4 = w1r[k4];
                acc = fmaf(w4.x, (float)hbuf[pb][k4 * 4 + 0], acc);
                acc = fmaf(w4.y, (float)hbuf[pb][k4 * 4 + 1], acc);
                acc = fmaf(w4.z, (float)hbuf[pb][k4 * 4 + 2], acc);
                acc = fmaf(w4.w, (float)hbuf[pb][k4 * 4 + 3], acc);
            }
            ys[lane] = fmaxf(acc, 0.0f);
        }
        asm volatile("s_waitcnt lgkmcnt(0)" ::: "memory");
        if (lane == 0) {
            float acc2 = b2[0];
            #pragma unroll
            for (int j = 0; j < 32; ++j) acc2 = fmaf(W2[j], ys[j], acc2);
            out[blockIdx.x * 4 + pb] = sigmoidf_(acc2);
        }
        asm volatile("s_waitcnt lgkmcnt(0)" ::: "memory");
    }
}

// ---------------------------------------------------------------------------
// Fallback: round-1 fused fp32 kernel (used only if workspace too small).
// ---------------------------------------------------------------------------
__global__ __launch_bounds__(256, 2)
void lstm_fused_kernel(const float* __restrict__ x,
                       const float* __restrict__ W_ih,
                       const float* __restrict__ W_hh,
                       const float* __restrict__ b_ih,
                       const float* __restrict__ b_hh,
                       const float* __restrict__ W1,
                       const float* __restrict__ b1,
                       const float* __restrict__ W2,
                       const float* __restrict__ b2,
                       float* __restrict__ out)
{
    const int b = blockIdx.x;
    const int g = threadIdx.x;

    __shared__ __align__(16) float xs[D_];
    __shared__ __align__(16) float hs[H_];
    __shared__ __align__(16) float gts[G_];
    __shared__ __align__(16) float yss[32];

    float wih[D_];
    float whhr[H_];
    {
        const float4* wr = (const float4*)(W_ih + (size_t)g * D_);
        #pragma unroll
        for (int k = 0; k < D_ / 4; ++k) {
            float4 v = wr[k];
            wih[4*k+0] = v.x; wih[4*k+1] = v.y;
            wih[4*k+2] = v.z; wih[4*k+3] = v.w;
        }
    }
    {
        const float4* wr = (const float4*)(W_hh + (size_t)g * H_);
        #pragma unroll
        for (int k = 0; k < H_ / 4; ++k) {
            float4 v = wr[k];
            whhr[4*k+0] = v.x; whhr[4*k+1] = v.y;
            whhr[4*k+2] = v.z; whhr[4*k+3] = v.w;
        }
    }
    const float bg  = b_ih[g] + b_hh[g];
    const int   cls = g >> 6;

    float c = 0.0f;
    if (g < H_) hs[g] = 0.0f;

    const float* __restrict__ xrow = x + (size_t)b * T_ * D_;

    for (int t = 0; t < T_; ++t) {
        if (g < D_) xs[g] = xrow[(size_t)t * D_ + g];
        __syncthreads();

        float a0 = bg, a1 = 0.f, a2 = 0.f, a3 = 0.f;
        const float4* xs4 = (const float4*)xs;
        #pragma unroll
        for (int k = 0; k < D_ / 4; ++k) {
            float4 v = xs4[k];
            a0 = fmaf(wih[4*k+0], v.x, a0);
            a1 = fmaf(wih[4*k+1], v.y, a1);
            a2 = fmaf(wih[4*k+2], v.z, a2);
            a3 = fmaf(wih[4*k+3], v.w, a3);
        }
        const float4* hs4 = (const float4*)hs;
        #pragma unroll
        for (int k = 0; k < H_ / 4; ++k) {
            float4 v = hs4[k];
            a0 = fmaf(whhr[4*k+0], v.x, a0);
            a1 = fmaf(whhr[4*k+1], v.y, a1);
            a2 = fmaf(whhr[4*k+2], v.z, a2);
            a3 = fmaf(whhr[4*k+3], v.w, a3);
        }
        float acc = (a0 + a1) + (a2 + a3);
        gts[g] = (cls == 2) ? tanhf_(acc) : sigmoidf_(acc);
        __syncthreads();

        if (g < H_) {
            float gi = gts[g];
            float gf = gts[H_ + g];
            float gg = gts[2 * H_ + g];
            float go = gts[3 * H_ + g];
            c = fmaf(gf, c, gi * gg);
            hs[g] = go * tanhf_(c);
        }
    }
    __syncthreads();

    if (g < 32) {
        float acc = b1[g];
        const float* w1r = W1 + g * H_;
        #pragma unroll
        for (int k = 0; k < H_; ++k) acc = fmaf(w1r[k], hs[k], acc);
        yss[g] = fmaxf(acc, 0.0f);
    }
    __syncthreads();
    if (g == 0) {
        float acc = b2[0];
        #pragma unroll
        for (int k = 0; k < 32; ++k) acc = fmaf(W2[k], yss[k], acc);
        out[b] = sigmoidf_(acc);
    }
}

extern "C" void kernel_launch(void* const* d_in, const int* in_sizes, int n_in,
                              void* d_out, int out_size, void* d_ws, size_t ws_size,
                              hipStream_t stream) {
    const float* x    = (const float*)d_in[0];
    const float* W_ih = (const float*)d_in[1];
    const float* W_hh = (const float*)d_in[2];
    const float* b_ih = (const float*)d_in[3];
    const float* b_hh = (const float*)d_in[4];
    const float* W1   = (const float*)d_in[5];
    const float* b1   = (const float*)d_in[6];
    const float* W2   = (const float*)d_in[7];
    const float* b2   = (const float*)d_in[8];
    float* out = (float*)d_out;

    const size_t xp_bytes = (size_t)M_ * G_ * sizeof(unsigned short);  // 134 MB

    if (ws_size >= xp_bytes) {
        unsigned short* xp = (unsigned short*)d_ws;
        xproj_f16_kernel<<<dim3(16, 64), dim3(256), 0, stream>>>(
            x, W_ih, b_ih, b_hh, xp);
        rec_mfma_kernel<<<dim3(B_ / 4), dim3(64), 0, stream>>>(
            xp, W_hh, W1, b1, W2, b2, out);
    } else {
        lstm_fused_kernel<<<dim3(B_), dim3(256), 0, stream>>>(
            x, W_ih, W_hh, b_ih, b_hh, W1, b1, W2, b2, out);
    }
}

// Round 11
// 383.947 us; speedup vs baseline: 1.6346x; 1.6346x over previous
//
#include <hip/hip_runtime.h>
#include <math.h>

// Problem constants: B=1024, T=256, D=128, H=64, 4H=256
constexpr int B_ = 1024;
constexpr int T_ = 256;
constexpr int D_ = 128;
constexpr int H_ = 64;
constexpr int G_ = 256;
constexpr int M_ = B_ * T_;

typedef short     v8s __attribute__((ext_vector_type(8)));   // 8 bf16
typedef float     v4f __attribute__((ext_vector_type(4)));   // MFMA acc
typedef _Float16  h2  __attribute__((ext_vector_type(2)));   // packed f16

__device__ __forceinline__ float sigmoidf_(float x) {
    return 1.0f / (1.0f + __expf(-x));
}
// tanh(x) = 2*sigmoid(2x) - 1 ; overflow-safe at both ends
__device__ __forceinline__ float tanhf_(float x) {
    return fmaf(2.0f, 1.0f / (1.0f + __expf(-2.0f * x)), -1.0f);
}
__device__ __forceinline__ unsigned short f2bf(float f) {   // RNE f32->bf16
    unsigned u = __float_as_uint(f);
    u = (u + 0x7fffu + ((u >> 16) & 1u)) >> 16;
    return (unsigned short)u;
}
__device__ __forceinline__ v8s pack8(float4 a, float4 b) {
    v8s r;
    r[0] = (short)f2bf(a.x); r[1] = (short)f2bf(a.y);
    r[2] = (short)f2bf(a.z); r[3] = (short)f2bf(a.w);
    r[4] = (short)f2bf(b.x); r[5] = (short)f2bf(b.y);
    r[6] = (short)f2bf(b.z); r[7] = (short)f2bf(b.w);
    return r;
}
__device__ __forceinline__ unsigned pkh2(float a, float b) {  // 2xf32 -> packed f16
    h2 v; v[0] = (_Float16)a; v[1] = (_Float16)b;
    return __builtin_bit_cast(unsigned, v);
}
// f16x2 dot with f32 accumulate (v_dot2_f32_f16); safe fallback if missing
__device__ __forceinline__ float fdot2_(unsigned a, unsigned b, float c) {
#if __has_builtin(__builtin_amdgcn_fdot2)
    return __builtin_amdgcn_fdot2(__builtin_bit_cast(h2, a),
                                  __builtin_bit_cast(h2, b), c, false);
#else
    h2 ha = __builtin_bit_cast(h2, a), hb = __builtin_bit_cast(h2, b);
    return c + (float)ha[0] * (float)hb[0] + (float)ha[1] * (float)hb[1];
#endif
}

// ---------------------------------------------------------------------------
// Phase 1 (R11): the measured-good 113us xproj with THREE minimal-delta
// pipeline fixes (mapping/tile/store path untouched -- R5's regression came
// from changing the mapping, not from pipelining):
//  1. xs double-buffered + next x-tile prefetched into registers BEFORE the
//     barrier -> tile loads overlap MFMA+store of the previous iteration.
//  2. Both __syncthreads() -> raw s_barrier + lgkmcnt(0): vmcnt NOT drained,
//     so prefetch loads stay in flight across barriers (proven rec pattern).
//  3. 3 blocks/CU (__launch_bounds__(256,3), VGPR cap ~170 >> ~120 used, no
//     spill risk per R8) for more cross-block latency hiding.
// ---------------------------------------------------------------------------
__global__ __launch_bounds__(256, 3)
void xproj_dbuf_kernel(const float* __restrict__ x,       // [B,T,D]
                       const float* __restrict__ W_ih,    // [256,128]
                       const float* __restrict__ b_ih,    // [256]
                       const float* __restrict__ b_hh,    // [256]
                       unsigned short* __restrict__ xp)   // [B][T][256] f16
{
    const int tch  = blockIdx.x;     // 0..15 : t = tch*16 + tl
    const int bblk = blockIdx.y;     // 0..63 : batches bblk*16..+15
    const int tid  = threadIdx.x;
    const int wv   = tid >> 6;
    const int lane = tid & 63;
    const int q    = lane >> 4;
    const int ml   = lane & 15;

    __shared__ __align__(16) unsigned short xs[2][16][136]; // x tile bf16, dbuf
    __shared__ __align__(16) unsigned short tbuf[16][272];  // [batch][gate] f16

    // ---- wave-resident A-frags + bias: gate tiles gt = cls*4 + wv ----
    v8s afr[4][4];   // [cls][ks]
    v4f bias[4];
    #pragma unroll
    for (int cls = 0; cls < 4; ++cls) {
        const int gr = (cls * 4 + wv) * 16 + ml;       // A m-index = ml
        #pragma unroll
        for (int ks = 0; ks < 4; ++ks) {
            const float* p = W_ih + (size_t)gr * D_ + ks * 32 + q * 8;
            afr[cls][ks] = pack8(((const float4*)p)[0], ((const float4*)p)[1]);
        }
        #pragma unroll
        for (int r = 0; r < 4; ++r) {
            const int g2 = (cls * 4 + wv) * 16 + q * 4 + r;   // C row = q*4+r
            bias[cls][r] = b_ih[g2] + b_hh[g2];
        }
    }

    // staging geometry: thread covers rows {tid>>5, 8+(tid>>5)}, col tid&31
    const int c4   = tid & 31;
    const int srow = tid >> 5;

    // ---- prologue: prefetch tile tl=0 into registers ----
    float4 pr[2];
    #pragma unroll
    for (int i = 0; i < 2; ++i) {
        const int row = srow + i * 8;
        pr[i] = ((const float4*)(x + ((size_t)(bblk * 16 + row) * T_
                                      + tch * 16) * D_))[c4];
    }

    for (int tl = 0; tl < 16; ++tl) {
        const int par = tl & 1;

        // ---- stage tile tl from regs (cvt forces vmcnt wait naturally) ----
        #pragma unroll
        for (int i = 0; i < 2; ++i) {
            const int row = srow + i * 8;
            short4 s;
            s.x = (short)f2bf(pr[i].x); s.y = (short)f2bf(pr[i].y);
            s.z = (short)f2bf(pr[i].z); s.w = (short)f2bf(pr[i].w);
            *(short4*)&xs[par][row][c4 * 4] = s;
        }

        // ---- issue prefetch for tile tl+1 (in flight across barriers) ----
        if (tl < 15) {
            #pragma unroll
            for (int i = 0; i < 2; ++i) {
                const int row = srow + i * 8;
                pr[i] = ((const float4*)(x + ((size_t)(bblk * 16 + row) * T_
                                              + tch * 16 + tl + 1) * D_))[c4];
            }
        }

        // bar1: xs[par] ready (LDS-only fence; vmcnt NOT drained)
        asm volatile("s_waitcnt lgkmcnt(0)" ::: "memory");
        __builtin_amdgcn_s_barrier();
        asm volatile("" ::: "memory");

        // ---- MFMA: 4 C-tiles per wave, K=128 ----
        v4f acc[4];
        #pragma unroll
        for (int cls = 0; cls < 4; ++cls) acc[cls] = bias[cls];
        #pragma unroll
        for (int ks = 0; ks < 4; ++ks) {
            v8s bf = *(const v8s*)&xs[par][ml][ks * 32 + q * 8]; // B: n=ml, k
            #pragma unroll
            for (int cls = 0; cls < 4; ++cls)
                acc[cls] = __builtin_amdgcn_mfma_f32_16x16x32_bf16(
                    afr[cls][ks], bf, acc[cls], 0, 0, 0);
        }

        // ---- pack f16 -> tbuf[batch=ml][gate] ----
        #pragma unroll
        for (int cls = 0; cls < 4; ++cls) {
            uint2 pk;
            pk.x = pkh2(acc[cls][0], acc[cls][1]);
            pk.y = pkh2(acc[cls][2], acc[cls][3]);
            *(uint2*)&tbuf[ml][cls * 64 + wv * 16 + q * 4] = pk;
        }

        // bar2: tbuf ready (also drains this iter's MFMA ds_reads)
        asm volatile("s_waitcnt lgkmcnt(0)" ::: "memory");
        __builtin_amdgcn_s_barrier();
        asm volatile("" ::: "memory");

        // ---- coalesced store: thread covers 16 gates of one (b,t) row ----
        // tbuf WAR vs next iter is safe: these ds_reads drain at next bar1's
        // lgkmcnt(0) before any wave passes bar1 and rewrites tbuf.
        {
            const int br = tid >> 4, seg = tid & 15;
            uint4 r0 = *(const uint4*)&tbuf[br][seg * 16];
            uint4 r1 = *(const uint4*)&tbuf[br][seg * 16 + 8];
            unsigned short* orow = xp + ((size_t)(bblk * 16 + br) * T_
                                         + tch * 16 + tl) * G_ + seg * 16;
            *(uint4*)orow       = r0;
            *(uint4*)(orow + 8) = r1;
        }
    }
}

// ---------------------------------------------------------------------------
// Phase 2 (R1 measured-good, 168 us -- FINAL, do not touch): one 64-lane
// wave per batch. Lane l owns gate rows {l, 64+l, 128+l, 192+l}; cell update
// lane-local; W_hh resident as packed f16 (128 VGPR); h exchanged via 128B
// LDS + bare lgkmcnt fence (no barrier, no vmcnt drain). Measured dead ends:
// barrier-split (R4), f32 weights (R6), SGPR broadcast (R7), 8-wave packing
// (R8/R9: 512-thr blocks pin VGPR=128 -> spill), MFMA recurrence (R10:
// 4x less parallelism + uncoalesced xp loads).
// ---------------------------------------------------------------------------
__global__ __launch_bounds__(64, 1)
void rec_wave_kernel(const unsigned short* __restrict__ xp,  // [B][T][256] f16
                     const float* __restrict__ W_hh,   // [256,64]
                     const float* __restrict__ W1,     // [32,64]
                     const float* __restrict__ b1,     // [32]
                     const float* __restrict__ W2,     // [1,32]
                     const float* __restrict__ b2,     // [1]
                     float* __restrict__ out)          // [B]
{
    const int b    = blockIdx.x;
    const int lane = threadIdx.x;    // 0..63

    __shared__ __align__(16) unsigned hb[2][32];   // h as 64 f16, dbuf
    __shared__ float hf[H_];
    __shared__ float ys[32];

    // ---- W_hh rows {lane, 64+lane, 128+lane, 192+lane} -> 32 uint4 ----
    uint4 wp[4][8];
    #pragma unroll
    for (int r = 0; r < 4; ++r) {
        const float* p = W_hh + (size_t)(r * 64 + lane) * H_;
        #pragma unroll
        for (int k8 = 0; k8 < 8; ++k8) {
            float4 v0 = ((const float4*)(p + k8 * 8))[0];
            float4 v1 = ((const float4*)(p + k8 * 8))[1];
            wp[r][k8].x = pkh2(v0.x, v0.y);
            wp[r][k8].y = pkh2(v0.z, v0.w);
            wp[r][k8].z = pkh2(v1.x, v1.y);
            wp[r][k8].w = pkh2(v1.z, v1.w);
        }
    }

    if (lane < 32) { hb[0][lane] = 0u; hb[1][lane] = 0u; }  // h(0) = 0
    float c = 0.0f, hval = 0.0f;

    const unsigned short* __restrict__ xptr = xp + (size_t)b * T_ * G_ + lane;
    // preload t=0 gates (coalesced 128B per 64-lane load, x4)
    unsigned short xv0 = xptr[0],   xv1 = xptr[64];
    unsigned short xv2 = xptr[128], xv3 = xptr[192];
    __syncthreads();   // once: hb zeros visible

    for (int t = 0; t < T_; ++t) {
        // ---- prefetch next step's xp (consumed after this step's matvec) ----
        const unsigned short* xnp =
            xptr + (size_t)((t + 1 < T_) ? t + 1 : T_ - 1) * G_;
        unsigned short xn0 = xnp[0],   xn1 = xnp[64];
        unsigned short xn2 = xnp[128], xn3 = xnp[192];

        // ---- matvec: 4 gate rows x K=64, f16 dot2, f32 accumulate ----
        const int par = t & 1;
        const uint4* hb4 = (const uint4*)hb[par];
        float a0[4] = {0.f, 0.f, 0.f, 0.f};
        float a1[4] = {0.f, 0.f, 0.f, 0.f};
        #pragma unroll
        for (int k8 = 0; k8 < 8; ++k8) {
            uint4 hv = hb4[k8];              // broadcast b128, conflict-free
            #pragma unroll
            for (int r = 0; r < 4; ++r) {
                a0[r] = fdot2_(wp[r][k8].x, hv.x, a0[r]);
                a1[r] = fdot2_(wp[r][k8].y, hv.y, a1[r]);
                a0[r] = fdot2_(wp[r][k8].z, hv.z, a0[r]);
                a1[r] = fdot2_(wp[r][k8].w, hv.w, a1[r]);
            }
        }
        float pre0 = (float)__builtin_bit_cast(_Float16, xv0) + (a0[0] + a1[0]);
        float pre1 = (float)__builtin_bit_cast(_Float16, xv1) + (a0[1] + a1[1]);
        float pre2 = (float)__builtin_bit_cast(_Float16, xv2) + (a0[2] + a1[2]);
        float pre3 = (float)__builtin_bit_cast(_Float16, xv3) + (a0[3] + a1[3]);

        // ---- lane-local gate activations + cell update ----
        float gi = sigmoidf_(pre0);
        float gf = sigmoidf_(pre1);
        float gg = tanhf_(pre2);
        float go = sigmoidf_(pre3);
        c    = fmaf(gf, c, gi * gg);
        hval = go * tanhf_(c);

        // ---- publish h(t+1): 2B/lane, then LDS-only fence (no barrier) ----
        ((_Float16*)hb[par ^ 1])[lane] = (_Float16)hval;
        asm volatile("s_waitcnt lgkmcnt(0)" ::: "memory");

        xv0 = xn0; xv1 = xn1; xv2 = xn2; xv3 = xn3;
    }

    // ---- head (once) ----
    hf[lane] = hval;
    __syncthreads();
    if (lane < 32) {
        float acc = b1[lane];
        const float4* w1r = (const float4*)(W1 + (size_t)lane * H_);
        #pragma unroll
        for (int k4 = 0; k4 < 16; ++k4) {
            float4 h4 = *(const float4*)&hf[k4 * 4];
            float4 w4 = w1r[k4];
            acc = fmaf(w4.x, h4.x, acc); acc = fmaf(w4.y, h4.y, acc);
            acc = fmaf(w4.z, h4.z, acc); acc = fmaf(w4.w, h4.w, acc);
        }
        ys[lane] = fmaxf(acc, 0.0f);
    }
    __syncthreads();
    if (lane == 0) {
        float acc = b2[0];
        #pragma unroll
        for (int j = 0; j < 32; ++j) acc = fmaf(W2[j], ys[j], acc);
        out[b] = sigmoidf_(acc);
    }
}

// ---------------------------------------------------------------------------
// Fallback: round-1 fused fp32 kernel (used only if workspace too small).
// ---------------------------------------------------------------------------
__global__ __launch_bounds__(256, 2)
void lstm_fused_kernel(const float* __restrict__ x,
                       const float* __restrict__ W_ih,
                       const float* __restrict__ W_hh,
                       const float* __restrict__ b_ih,
                       const float* __restrict__ b_hh,
                       const float* __restrict__ W1,
                       const float* __restrict__ b1,
                       const float* __restrict__ W2,
                       const float* __restrict__ b2,
                       float* __restrict__ out)
{
    const int b = blockIdx.x;
    const int g = threadIdx.x;

    __shared__ __align__(16) float xs[D_];
    __shared__ __align__(16) float hs[H_];
    __shared__ __align__(16) float gts[G_];
    __shared__ __align__(16) float yss[32];

    float wih[D_];
    float whhr[H_];
    {
        const float4* wr = (const float4*)(W_ih + (size_t)g * D_);
        #pragma unroll
        for (int k = 0; k < D_ / 4; ++k) {
            float4 v = wr[k];
            wih[4*k+0] = v.x; wih[4*k+1] = v.y;
            wih[4*k+2] = v.z; wih[4*k+3] = v.w;
        }
    }
    {
        const float4* wr = (const float4*)(W_hh + (size_t)g * H_);
        #pragma unroll
        for (int k = 0; k < H_ / 4; ++k) {
            float4 v = wr[k];
            whhr[4*k+0] = v.x; whhr[4*k+1] = v.y;
            whhr[4*k+2] = v.z; whhr[4*k+3] = v.w;
        }
    }
    const float bg  = b_ih[g] + b_hh[g];
    const int   cls = g >> 6;

    float c = 0.0f;
    if (g < H_) hs[g] = 0.0f;

    const float* __restrict__ xrow = x + (size_t)b * T_ * D_;

    for (int t = 0; t < T_; ++t) {
        if (g < D_) xs[g] = xrow[(size_t)t * D_ + g];
        __syncthreads();

        float a0 = bg, a1 = 0.f, a2 = 0.f, a3 = 0.f;
        const float4* xs4 = (const float4*)xs;
        #pragma unroll
        for (int k = 0; k < D_ / 4; ++k) {
            float4 v = xs4[k];
            a0 = fmaf(wih[4*k+0], v.x, a0);
            a1 = fmaf(wih[4*k+1], v.y, a1);
            a2 = fmaf(wih[4*k+2], v.z, a2);
            a3 = fmaf(wih[4*k+3], v.w, a3);
        }
        const float4* hs4 = (const float4*)hs;
        #pragma unroll
        for (int k = 0; k < H_ / 4; ++k) {
            float4 v = hs4[k];
            a0 = fmaf(whhr[4*k+0], v.x, a0);
            a1 = fmaf(whhr[4*k+1], v.y, a1);
            a2 = fmaf(whhr[4*k+2], v.z, a2);
            a3 = fmaf(whhr[4*k+3], v.w, a3);
        }
        float acc = (a0 + a1) + (a2 + a3);
        gts[g] = (cls == 2) ? tanhf_(acc) : sigmoidf_(acc);
        __syncthreads();

        if (g < H_) {
            float gi = gts[g];
            float gf = gts[H_ + g];
            float gg = gts[2 * H_ + g];
            float go = gts[3 * H_ + g];
            c = fmaf(gf, c, gi * gg);
            hs[g] = go * tanhf_(c);
        }
    }
    __syncthreads();

    if (g < 32) {
        float acc = b1[g];
        const float* w1r = W1 + g * H_;
        #pragma unroll
        for (int k = 0; k < H_; ++k) acc = fmaf(w1r[k], hs[k], acc);
        yss[g] = fmaxf(acc, 0.0f);
    }
    __syncthreads();
    if (g == 0) {
        float acc = b2[0];
        #pragma unroll
        for (int k = 0; k < 32; ++k) acc = fmaf(W2[k], yss[k], acc);
        out[b] = sigmoidf_(acc);
    }
}

extern "C" void kernel_launch(void* const* d_in, const int* in_sizes, int n_in,
                              void* d_out, int out_size, void* d_ws, size_t ws_size,
                              hipStream_t stream) {
    const float* x    = (const float*)d_in[0];
    const float* W_ih = (const float*)d_in[1];
    const float* W_hh = (const float*)d_in[2];
    const float* b_ih = (const float*)d_in[3];
    const float* b_hh = (const float*)d_in[4];
    const float* W1   = (const float*)d_in[5];
    const float* b1   = (const float*)d_in[6];
    const float* W2   = (const float*)d_in[7];
    const float* b2   = (const float*)d_in[8];
    float* out = (float*)d_out;

    const size_t xp_bytes = (size_t)M_ * G_ * sizeof(unsigned short);  // 134 MB

    if (ws_size >= xp_bytes) {
        unsigned short* xp = (unsigned short*)d_ws;
        xproj_dbuf_kernel<<<dim3(16, 64), dim3(256), 0, stream>>>(
            x, W_ih, b_ih, b_hh, xp);
        rec_wave_kernel<<<dim3(B_), dim3(64), 0, stream>>>(
            xp, W_hh, W1, b1, W2, b2, out);
    } else {
        lstm_fused_kernel<<<dim3(B_), dim3(256), 0, stream>>>(
            x, W_ih, W_hh, b_ih, b_hh, W1, b1, W2, b2, out);
    }
}